// Round 10
// baseline (329.997 us; speedup 1.0000x reference)
//
#include <hip/hip_runtime.h>
#include <hip/hip_bf16.h>
#include <hip/hip_cooperative_groups.h>

namespace cg = cooperative_groups;

#define N_NODES 4096
#define FIN     512
#define FOUT    256
#define NSPLIT  4
#define NTILES  ((N_NODES / NSPLIT) / 64)   // 16
#define ITILE   128                         // i-rows per attn block

typedef __attribute__((ext_vector_type(8))) short bf16x8s;
typedef __attribute__((ext_vector_type(4))) float f32x4;
typedef __attribute__((ext_vector_type(8))) unsigned short u16x8;
typedef unsigned short u16;

__device__ inline u16 f2b(float f) {
    union { float f; unsigned int u; } v; v.f = f;
    unsigned int r = v.u + 0x7fffu + ((v.u >> 16) & 1u);   // RTNE
    return (u16)(r >> 16);
}

__device__ inline u16 f2b_fast(float f) {                  // RTNE via HW cvt
    return __bfloat16_as_ushort(__float2bfloat16(f));
}

// ---------------------------------------------------------------------------
// ONE cooperative kernel: prep -> gemm -> attn -> reduce, separated by
// grid.sync(). 256 blocks x 1024 threads, 64 KB LDS, co-resident (1/CU).
// Phase bodies are the proven R8 implementations re-indexed.
// ---------------------------------------------------------------------------
__global__ __launch_bounds__(1024) void fused_kernel(
    const float* __restrict__ h,
    const int* __restrict__ adj_n, const int* __restrict__ adj_d,
    const float* __restrict__ Wn, const float* __restrict__ a1n, const float* __restrict__ a2n,
    const float* __restrict__ Wd, const float* __restrict__ a1d, const float* __restrict__ a2d,
    u16* __restrict__ hb, u16* __restrict__ WTb, u16* __restrict__ WhT,
    float* __restrict__ s1, float* __restrict__ s2,
    float* __restrict__ num_ws, float* __restrict__ den_ws,
    float* __restrict__ out)
{
    __shared__ __align__(16) u16 smem[32768];   // 64 KB pool, re-used per phase
    cg::grid_group grid = cg::this_grid();
    const int B = blockIdx.x;                   // 0..255
    const int t = threadIdx.x;                  // 0..1023

    // ===== phase 0: prep =====
    {   // h convert: 4096x512 fp32 -> bf16, 8 per thread, exact cover
        int idx = (B * 1024 + t) * 8;
        float4 f0 = *(const float4*)&h[idx];
        float4 f1 = *(const float4*)&h[idx + 4];
        u16x8 o;
        o[0]=f2b(f0.x); o[1]=f2b(f0.y); o[2]=f2b(f0.z); o[3]=f2b(f0.w);
        o[4]=f2b(f1.x); o[5]=f2b(f1.y); o[6]=f2b(f1.z); o[7]=f2b(f1.w);
        *(u16x8*)&hb[idx] = o;
    }
    if (B < 16) {                               // W transpose: 64 ids, 4 groups/block
        const int g = t >> 8, tg = t & 255;
        const int id = B * 4 + g;               // 0..63
        const int kx = id & 7, ny = (id >> 3) & 3, bb = id >> 5;
        const float* W = bb ? Wd : Wn;
        const int k0 = kx * 64, n0 = ny * 64;
        u16* tl = smem + g * 4608;              // 64*72 u16 per group
        int kr = tg >> 2, nc0 = (tg & 3) * 16;
        const float* src = W + (size_t)(k0 + kr) * FOUT + n0 + nc0;
        #pragma unroll
        for (int jv = 0; jv < 4; ++jv) {
            float4 f = *(const float4*)(src + jv * 4);
            tl[(nc0 + jv * 4 + 0) * 72 + kr] = f2b(f.x);
            tl[(nc0 + jv * 4 + 1) * 72 + kr] = f2b(f.y);
            tl[(nc0 + jv * 4 + 2) * 72 + kr] = f2b(f.z);
            tl[(nc0 + jv * 4 + 3) * 72 + kr] = f2b(f.w);
        }
        __syncthreads();
        int n = tg >> 2, kc0 = (tg & 3) * 16;
        u16* dst = WTb + ((size_t)bb << 17) + (size_t)(n0 + n) * FIN + k0 + kc0;
        *(uint4*)dst       = *(uint4*)&tl[n * 72 + kc0];
        *(uint4*)(dst + 8) = *(uint4*)&tl[n * 72 + kc0 + 8];
    } else if (B == 16) {                       // zero s1,s2 (16384 floats)
        float4 z = {0.f, 0.f, 0.f, 0.f};
        float4* p4 = (float4*)s1;               // s2 contiguous after s1
        #pragma unroll
        for (int k = 0; k < 4; ++k) p4[k * 1024 + t] = z;
    }
    grid.sync();

    // ===== phase 1: wh_gemm (R0 64-K-tile form), 128 blocks x 4 groups =====
    if (B < 128) {
        const int g = t >> 8, tg = t & 255;
        u16* gbase = smem + g * 8192;           // 16 KB slice per group
        u16* a_lds = gbase;
        u16* b_lds = gbase + 4096;
        const int sub = B * 4 + g;              // 0..511
        const int i0 = (sub & 63) * 64, n0 = ((sub >> 6) & 3) * 64, bb = sub >> 8;
        const int lane = tg & 63, w = tg >> 6;
        const int q = lane >> 4, ln = lane & 15;
        const u16* wt = WTb + ((size_t)bb << 17);

        f32x4 acc[4];
        #pragma unroll
        for (int i = 0; i < 4; ++i) acc[i] = (f32x4){0.f, 0.f, 0.f, 0.f};

        for (int kt = 0; kt < 8; ++kt) {
            const int k0 = kt * 64;
            __syncthreads();
            #pragma unroll
            for (int it = 0; it < 2; ++it) {
                int chunk = it * 256 + tg;
                int r = chunk >> 3, kc = chunk & 7;
                const u16* gp = hb + (size_t)(i0 + r) * FIN + k0 + ((kc ^ (r & 7)) * 8);
                u16* l = a_lds + (it * 256 + w * 64) * 8;
                __builtin_amdgcn_global_load_lds(
                    (const __attribute__((address_space(1))) void*)gp,
                    (__attribute__((address_space(3))) void*)l, 16, 0, 0);
            }
            #pragma unroll
            for (int it = 0; it < 2; ++it) {
                int chunk = it * 256 + tg;
                int n = chunk >> 3, kc = chunk & 7;
                const u16* gp = wt + (size_t)(n0 + n) * FIN + k0 + ((kc ^ (n & 7)) * 8);
                u16* l = b_lds + (it * 256 + w * 64) * 8;
                __builtin_amdgcn_global_load_lds(
                    (const __attribute__((address_space(1))) void*)gp,
                    (__attribute__((address_space(3))) void*)l, 16, 0, 0);
            }
            __syncthreads();
            #pragma unroll
            for (int ks = 0; ks < 2; ++ks) {
                int sw = ((ks * 4 + q) ^ (ln & 7)) * 8;
                bf16x8s af = *(const bf16x8s*)&a_lds[(w * 16 + ln) * 64 + sw];
                #pragma unroll
                for (int nt = 0; nt < 4; ++nt) {
                    bf16x8s bfv = *(const bf16x8s*)&b_lds[(nt * 16 + ln) * 64 + sw];
                    acc[nt] = __builtin_amdgcn_mfma_f32_16x16x32_bf16(af, bfv, acc[nt], 0, 0, 0);
                }
            }
        }
        {
            const float* a1 = bb ? a1d : a1n;
            const float* a2 = bb ? a2d : a2n;
            float s1p[4] = {0.f, 0.f, 0.f, 0.f};
            float s2p[4] = {0.f, 0.f, 0.f, 0.f};
            #pragma unroll
            for (int nt = 0; nt < 4; ++nt) {
                float va1 = a1[n0 + nt * 16 + ln];
                float va2 = a2[n0 + nt * 16 + ln];
                #pragma unroll
                for (int r = 0; r < 4; ++r) {
                    s1p[r] += acc[nt][r] * va1;
                    s2p[r] += acc[nt][r] * va2;
                }
            }
            #pragma unroll
            for (int r = 0; r < 4; ++r) {
                #pragma unroll
                for (int off = 8; off >= 1; off >>= 1) {
                    s1p[r] += __shfl_xor(s1p[r], off);
                    s2p[r] += __shfl_xor(s2p[r], off);
                }
                if (ln == 0) {
                    int row = i0 + w * 16 + q * 4 + r;
                    atomicAdd(&s1[bb * N_NODES + row], s1p[r]);
                    atomicAdd(&s2[bb * N_NODES + row], s2p[r]);
                }
            }
        }
        __syncthreads();
        #pragma unroll
        for (int nt = 0; nt < 4; ++nt)
            #pragma unroll
            for (int r = 0; r < 4; ++r)
                gbase[(nt * 16 + ln) * 72 + (w * 16 + q * 4 + r)] = f2b(acc[nt][r]);
        __syncthreads();
        {
            const int nl = tg >> 2, is = (tg & 3) * 16;
            u16* dst = WhT + ((size_t)bb << 20) + (size_t)(n0 + nl) * N_NODES + i0 + is;
            *(uint4*)dst       = *(uint4*)&gbase[nl * 72 + is];
            *(uint4*)(dst + 8) = *(uint4*)&gbase[nl * 72 + is + 8];
        }
    }
    grid.sync();

    // ===== phase 2: attn (R8-exact) =====
    {
        u16* wht_lds = smem;                    // 16384 u16 = 32 KB
        u16* p_lds   = smem + 16384;            // 8192 u16 = 16 KB

        const int lane = t & 63, w = t >> 6;    // w 0..15
        const int q = lane >> 4, ln = lane & 15;
        const int ih = w >> 2;                  // i-quarter (32 rows)
        const int nq = w & 3;                   // n-quarter (64 cols)
        const int bb = B >> 7;                  // branch
        const int split = (B >> 5) & 3;
        const int i0 = (B & 31) * ITILE;

        const int* adjb = bb ? adj_d : adj_n;
        const u16* whtB = WhT + ((size_t)bb << 20);
        const float* s1b = s1 + bb * N_NODES;
        const float* s2b = s2 + bb * N_NODES;

        const int pr = t >> 3;                  // P row 0..127
        const int cw = t & 7;                   // P k-chunk 0..7
        const int pc = cw * 8;
        const float s1v = s1b[i0 + pr];
        const size_t arow = (size_t)(i0 + pr) * N_NODES + pc;
        const int swp = (cw ^ (pr & 7)) * 8;

        float den0 = 0.f;

        f32x4 acc[2][4];
        #pragma unroll
        for (int mt = 0; mt < 2; ++mt)
            #pragma unroll
            for (int nt = 0; nt < 4; ++nt) acc[mt][nt] = (f32x4){0.f, 0.f, 0.f, 0.f};

        const int jbase = split * (N_NODES / NSPLIT);

        int4 a0_pf = *(const int4*)&adjb[arow + jbase];
        int4 a1_pf = *(const int4*)&adjb[arow + jbase + 4];
        float4 sv0_pf = *(const float4*)&s2b[jbase + pc];
        float4 sv1_pf = *(const float4*)&s2b[jbase + pc + 4];

        for (int jt = 0; jt < NTILES; ++jt) {
            const int j0 = jbase + jt * 64;
            __syncthreads();
            #pragma unroll
            for (int it = 0; it < 2; ++it) {
                int chunk = it * 1024 + t;
                int n = chunk >> 3, kc = chunk & 7;
                const u16* gp = whtB + (size_t)n * N_NODES + j0 + ((kc ^ (n & 7)) * 8);
                u16* l = wht_lds + (it * 1024 + w * 64) * 8;
                __builtin_amdgcn_global_load_lds(
                    (const __attribute__((address_space(1))) void*)gp,
                    (__attribute__((address_space(3))) void*)l, 16, 0, 0);
            }
            int4 a0 = a0_pf, a1 = a1_pf;
            float4 sv0 = sv0_pf, sv1 = sv1_pf;
            if (jt < NTILES - 1) {
                const int jn = j0 + 64;
                a0_pf = *(const int4*)&adjb[arow + jn];
                a1_pf = *(const int4*)&adjb[arow + jn + 4];
                sv0_pf = *(const float4*)&s2b[jn + pc];
                sv1_pf = *(const float4*)&s2b[jn + pc + 4];
            }
            int v[8] = {a0.x, a0.y, a0.z, a0.w, a1.x, a1.y, a1.z, a1.w};
            float svf[8] = {sv0.x, sv0.y, sv0.z, sv0.w, sv1.x, sv1.y, sv1.z, sv1.w};
            float d = 0.f;
            u16x8 pk;
            #pragma unroll
            for (int jj = 0; jj < 8; ++jj) {
                float x = s1v + svf[jj];
                float p = (v[jj] > 0) ? __expf(fmaxf(x, 0.2f * x)) : 0.f;
                d += p;
                pk[jj] = f2b_fast(p);
            }
            d += __shfl_down(d, 4, 8);
            d += __shfl_down(d, 2, 8);
            d += __shfl_down(d, 1, 8);
            if ((t & 7) == 0) den0 += d;
            *(u16x8*)&p_lds[pr * 64 + swp] = pk;
            __syncthreads();
            #pragma unroll
            for (int ks = 0; ks < 2; ++ks) {
                int sw = ((ks * 4 + q) ^ (ln & 7)) * 8;
                bf16x8s af0 = *(const bf16x8s*)&p_lds[(ih * 32 + 0 * 16 + ln) * 64 + sw];
                bf16x8s af1 = *(const bf16x8s*)&p_lds[(ih * 32 + 1 * 16 + ln) * 64 + sw];
                #pragma unroll
                for (int nt = 0; nt < 4; ++nt) {
                    bf16x8s bfv = *(const bf16x8s*)&wht_lds[(nq * 64 + nt * 16 + ln) * 64 + sw];
                    acc[0][nt] = __builtin_amdgcn_mfma_f32_16x16x32_bf16(af0, bfv, acc[0][nt], 0, 0, 0);
                    acc[1][nt] = __builtin_amdgcn_mfma_f32_16x16x32_bf16(af1, bfv, acc[1][nt], 0, 0, 0);
                }
            }
        }
        const size_t pbase = (size_t)(bb * NSPLIT + split) * N_NODES;
        #pragma unroll
        for (int mt = 0; mt < 2; ++mt)
            #pragma unroll
            for (int r = 0; r < 4; ++r) {
                int row = ih * 32 + mt * 16 + q * 4 + r;
                #pragma unroll
                for (int nt = 0; nt < 4; ++nt)
                    num_ws[(pbase + i0 + row) * FOUT + nq * 64 + nt * 16 + ln] = acc[mt][nt][r];
            }
        if ((t & 7) == 0) den_ws[pbase + i0 + pr] = den0;
    }
    grid.sync();

    // ===== phase 3: reduce (R8-exact) =====
    {
        int gid = B * 1024 + t;
        int i = gid >> 6;
        int f4 = (gid & 63) * 4;
        float4 o = {0.f, 0.f, 0.f, 0.f};
        #pragma unroll
        for (int bb = 0; bb < 2; ++bb) {
            float4 numv = {0.f, 0.f, 0.f, 0.f};
            float den = 0.f;
            #pragma unroll
            for (int s = 0; s < NSPLIT; ++s) {
                const float4 v = *(const float4*)&num_ws[((size_t)(bb * NSPLIT + s) * N_NODES + i) * FOUT + f4];
                numv.x += v.x; numv.y += v.y; numv.z += v.z; numv.w += v.w;
                den += den_ws[(size_t)(bb * NSPLIT + s) * N_NODES + i];
            }
            float inv = 1.0f / den;
            float e0 = numv.x * inv, e1 = numv.y * inv, e2 = numv.z * inv, e3 = numv.w * inv;
            o.x += (e0 > 0.f) ? e0 : expm1f(e0);
            o.y += (e1 > 0.f) ? e1 : expm1f(e1);
            o.z += (e2 > 0.f) ? e2 : expm1f(e2);
            o.w += (e3 > 0.f) ? e3 : expm1f(e3);
        }
        *(float4*)&out[(size_t)i * FOUT + f4] = o;
    }
}

extern "C" void kernel_launch(void* const* d_in, const int* in_sizes, int n_in,
                              void* d_out, int out_size, void* d_ws, size_t ws_size,
                              hipStream_t stream) {
    const float* h    = (const float*)d_in[0];
    const int*   adjn = (const int*)d_in[1];
    const int*   adjd = (const int*)d_in[2];
    const float* Wn   = (const float*)d_in[4];
    const float* a1n  = (const float*)d_in[5];
    const float* a2n  = (const float*)d_in[6];
    const float* Wd   = (const float*)d_in[7];
    const float* a1d  = (const float*)d_in[8];
    const float* a2d  = (const float*)d_in[9];

    char* ws = (char*)d_ws;
    // [0,4M): WhT   [8M,8M+192K): s1,s2,den_ws
    // [8.25M,12.25M): hb   [12.25M,12.75M): WTb   (dead after gemm)
    // [8.25M,40.25M): num_ws (overlays hb/WTb; written by attn after gemm)
    u16*  WhT  = (u16*)ws;
    float* s1  = (float*)(ws + ((size_t)8 << 20));
    float* s2  = s1 + 2 * N_NODES;
    float* den = s2 + 2 * N_NODES;
    u16*  hb   = (u16*)(ws + ((size_t)8 << 20) + ((size_t)256 << 10));
    u16*  WTb  = (u16*)(ws + ((size_t)12 << 20) + ((size_t)256 << 10));
    float* num = (float*)(ws + ((size_t)8 << 20) + ((size_t)256 << 10));
    float* outp = (float*)d_out;

    void* args[] = {
        (void*)&h, (void*)&adjn, (void*)&adjd,
        (void*)&Wn, (void*)&a1n, (void*)&a2n,
        (void*)&Wd, (void*)&a1d, (void*)&a2d,
        (void*)&hb, (void*)&WTb, (void*)&WhT,
        (void*)&s1, (void*)&s2,
        (void*)&num, (void*)&den,
        (void*)&outp
    };
    hipLaunchCooperativeKernel((void*)fused_kernel, dim3(256), dim3(1024),
                               args, 0, stream);
}